// Round 13
// baseline (502.595 us; speedup 1.0000x reference)
//
#include <hip/hip_runtime.h>
#include <hip/hip_bf16.h>

#define DIM 768
#define NH 12
#define HD 64
#define SEQ 1024
#define BATCH 8
#define LOG2E 1.44269504f

typedef __bf16 bf16x8 __attribute__((ext_vector_type(8)));
typedef _Float16 f16x4 __attribute__((ext_vector_type(4)));
typedef float f32x4 __attribute__((ext_vector_type(4)));

// async global->LDS copy, 16 B per lane; LDS dest is wave-uniform base
// (+ lane*16 implicit). Source is per-lane.
__device__ __forceinline__ void gload_lds16(const __bf16* g, __bf16* l) {
  __builtin_amdgcn_global_load_lds(
      (const __attribute__((address_space(1))) void*)g,
      (__attribute__((address_space(3))) void*)l, 16, 0, 0);
}

// ---------------------------------------------------------------------------
// K-1: convert X fp32 -> bf16 (one-shot, ~38 MB traffic).
// ---------------------------------------------------------------------------
__global__ __launch_bounds__(256) void xcvt(
    const float* __restrict__ X, __bf16* __restrict__ Xb)
{
  const size_t i = ((size_t)blockIdx.x * 256 + threadIdx.x) * 8;
  float4 a0 = *(const float4*)(X + i);
  float4 a1 = *(const float4*)(X + i + 4);
  bf16x8 v = { (__bf16)a0.x, (__bf16)a0.y, (__bf16)a0.z, (__bf16)a0.w,
               (__bf16)a1.x, (__bf16)a1.y, (__bf16)a1.z, (__bf16)a1.w };
  *(bf16x8*)(Xb + i) = v;
}

// ---------------------------------------------------------------------------
// K0: transpose + cvt 768x768 fp32 W -> bf16 WT[n][k]. blockIdx.z selects.
// ---------------------------------------------------------------------------
__global__ __launch_bounds__(256) void wtrans(
    const float* __restrict__ Wq, const float* __restrict__ Wk,
    const float* __restrict__ Wv, const float* __restrict__ Wp,
    __bf16* __restrict__ Tq, __bf16* __restrict__ Tk,
    __bf16* __restrict__ Tv, __bf16* __restrict__ Tp)
{
  const int z = blockIdx.z;
  const float* W = (z==0) ? Wq : (z==1) ? Wk : (z==2) ? Wv : Wp;
  __bf16* T = (z==0) ? Tq : (z==1) ? Tk : (z==2) ? Tv : Tp;
  __shared__ float tile[32][33];
  const int t = threadIdx.x, tx = t & 31, ty = t >> 5;
  const int k0 = blockIdx.y * 32, n0 = blockIdx.x * 32;
#pragma unroll
  for (int u = 0; u < 4; ++u)
    tile[ty + u*8][tx] = W[(size_t)(k0 + ty + u*8) * DIM + n0 + tx];
  __syncthreads();
#pragma unroll
  for (int u = 0; u < 4; ++u)
    T[(size_t)(n0 + ty + u*8) * DIM + k0 + tx] = (__bf16)tile[tx][ty + u*8];
}

// ---------------------------------------------------------------------------
// K1: fused QKV projection, global_load_lds staging (R8 proven).
// ---------------------------------------------------------------------------
__global__ __launch_bounds__(256) void gemm_qkv(
    const __bf16* __restrict__ Xb, const __bf16* __restrict__ WT,
    __bf16* __restrict__ Qo, __bf16* __restrict__ Ko, _Float16* __restrict__ Vt2)
{
  __shared__ __bf16 As[128 * 32];
  __shared__ __bf16 Bs[128 * 32];

  const int t = threadIdx.x, lane = t & 63, w = t >> 6;
  const int n16 = lane & 15, q = lane >> 4;
  const int m0 = blockIdx.y * 128, n0 = blockIdx.x * 128;
  const int wm = (w >> 1) * 64, wn = (w & 1) * 64;

  const int srow = t >> 2, scol = (t & 3) * 8;
  const __bf16* Ag = Xb + (size_t)(m0 + srow) * DIM + scol;
  const __bf16* Bg = WT + (size_t)(n0 + srow) * DIM + scol;
  __bf16* AsW0 = &As[w * 512];
  __bf16* AsW1 = &As[2048 + w * 512];
  __bf16* BsW0 = &Bs[w * 512];
  __bf16* BsW1 = &Bs[2048 + w * 512];

  f32x4 acc[4][4];
#pragma unroll
  for (int mt = 0; mt < 4; ++mt)
#pragma unroll
    for (int nt = 0; nt < 4; ++nt) acc[mt][nt] = (f32x4){0.f,0.f,0.f,0.f};

  for (int kb = 0; kb < DIM; kb += 32) {
    __syncthreads();
    gload_lds16(Ag + kb, AsW0);
    gload_lds16(Ag + (size_t)64 * DIM + kb, AsW1);
    gload_lds16(Bg + kb, BsW0);
    gload_lds16(Bg + (size_t)64 * DIM + kb, BsW1);
    __syncthreads();

    bf16x8 af[4], bg[4];
#pragma unroll
    for (int mt = 0; mt < 4; ++mt)
      af[mt] = *(const bf16x8*)&As[(wm + mt*16 + n16) * 32 + q*8];
#pragma unroll
    for (int nt = 0; nt < 4; ++nt)
      bg[nt] = *(const bf16x8*)&Bs[(wn + nt*16 + n16) * 32 + q*8];
#pragma unroll
    for (int mt = 0; mt < 4; ++mt)
#pragma unroll
      for (int nt = 0; nt < 4; ++nt)
        acc[mt][nt] = __builtin_amdgcn_mfma_f32_16x16x32_bf16(af[mt], bg[nt], acc[mt][nt], 0, 0, 0);
  }

#pragma unroll
  for (int nt = 0; nt < 4; ++nt) {
    const int n = n0 + wn + nt*16 + n16;
    const int z = n / DIM, c = n % DIM;
    const int h = c >> 6, d = c & 63;
#pragma unroll
    for (int mt = 0; mt < 4; ++mt) {
#pragma unroll
      for (int r = 0; r < 4; ++r) {
        const int row = m0 + wm + mt*16 + q*4 + r;
        const int bb = row >> 10, ii = row & 1023;
        const float v = acc[mt][nt][r];
        if (z == 0)
          Qo[(((size_t)bb*NH + h)*SEQ + ii)*HD + d] = (__bf16)(v * 0.125f);
        else if (z == 1)
          Ko[(((size_t)bb*NH + h)*SEQ + ii)*HD + d] = (__bf16)v;
        else
          Vt2[((((size_t)bb*NH + h)*64 + (ii >> 4))*HD + d)*16 + (ii & 15)] = (_Float16)v;
      }
    }
  }
}

// accumulate premix for one head's score fragment s into a[12]
#define PREMIX_ACC(hh_, s_)                                              \
  do {                                                                   \
    const f32x4 w0_ = *(const f32x4*)&WlsT[(hh_)*12];                    \
    const f32x4 w1_ = *(const f32x4*)&WlsT[(hh_)*12 + 4];                \
    const f32x4 w2_ = *(const f32x4*)&WlsT[(hh_)*12 + 8];                \
    _Pragma("unroll")                                                    \
    for (int g_ = 0; g_ < 4; ++g_)                                       \
      _Pragma("unroll")                                                  \
      for (int r_ = 0; r_ < 4; ++r_) {                                   \
        a[g_][r_]   += w0_[g_] * (s_)[r_];                               \
        a[4+g_][r_] += w1_[g_] * (s_)[r_];                               \
        a[8+g_][r_] += w2_[g_] * (s_)[r_];                               \
      }                                                                  \
  } while (0)

// ---------------------------------------------------------------------------
// K2: fused talking-heads attention.
// Phase A: j-partitioned, barrier-free, in-register premix. Register-budget
// history: R10 full unroll -> 192-reg load hoist -> spill; R12 unroll 1 ->
// no ILP -> serial-chain bound (174 us). This round: explicit 2-deep
// double-buffer inside an unroll-1 h-loop — loads for step n+1 in flight
// while step n computes; peak live ~120 regs (c16+n16+a48+lsum12+wts).
// Phase B byte-identical to R8 (proven 257 us).
// ---------------------------------------------------------------------------
__global__ __launch_bounds__(256, 2) void attn_fused(
    const __bf16* __restrict__ Qg, const __bf16* __restrict__ Kg,
    const _Float16* __restrict__ Vt2,
    const float* __restrict__ Wl, const float* __restrict__ bl,
    const float* __restrict__ Ww, const float* __restrict__ bw,
    __bf16* __restrict__ Aout)
{
  __shared__ _Float16 Sl[2][12][324];    // f16 scores (phase B only)
  __shared__ _Float16 Pl[2][16 * 248];   // [buf][i*248 + g2*20 + j]
  __shared__ float WlsT[144];            // transposed premix wts * log2e [h*12+g]
  __shared__ float blS[12];              // premix bias * log2e
  __shared__ float Lx[4][12][16];        // per-wave partial l[g][i]

  const int t = threadIdx.x, lane = t & 63, w = t >> 6;
  const int n16 = lane & 15, q = lane >> 4;
  const int h0 = w * 3;
  const int b = blockIdx.x, i0 = blockIdx.y * 16;
  const size_t bbase = (size_t)b * NH * SEQ * HD;

  // stage transposed premix weights (once): WlsT[h*12+g] = Wl[g*12+h]*log2e
  if (t < 144) WlsT[(t % 12) * 12 + (t / 12)] = Wl[t] * LOG2E;
  if (t < 12)  blS[t] = bl[t] * LOG2E;

  // phase-B mix weights (MFMA path, proven mapping)
  f16x4 wlA, wwA;
  f32x4 blC, bwC;
#pragma unroll
  for (int j = 0; j < 4; ++j) {
    const int k = q*4 + j;
    wlA[j] = (n16 < 12 && k < 12) ? (_Float16)(Wl[n16*12 + k] * LOG2E) : (_Float16)0.f;
    wwA[j] = (n16 < 12 && k < 12) ? (_Float16)Ww[n16*12 + k] : (_Float16)0.f;
    blC[j] = (k < 12) ? bl[k] * LOG2E : 0.f;
    bwC[j] = (k < 12) ? bw[k] : 0.f;
  }

  const f32x4 z4 = {0.f, 0.f, 0.f, 0.f};
  __syncthreads();   // WlsT/blS visible

  // ========== Phase A: barrier-free, j-partitioned, in-register premix ====
  float lsum[12];
#pragma unroll
  for (int g = 0; g < 12; ++g) lsum[g] = 0.f;

  // per-lane bases (h=0); h-step adds SEQ*HD
  const __bf16* kbase = Kg + bbase + ((size_t)(w*16) + n16)*HD + q*8;
  const __bf16* qbase = Qg + bbase + ((size_t)(i0 + n16))*HD + q*8;
  const size_t HSTEP = (size_t)SEQ * HD;

  // prime: (tt=0, h=0) in c-buf
  bf16x8 c0 = *(const bf16x8*)kbase;
  bf16x8 c1 = *(const bf16x8*)(kbase + 32);
  bf16x8 c2 = *(const bf16x8*)qbase;
  bf16x8 c3 = *(const bf16x8*)(qbase + 32);

#pragma unroll 1
  for (int tt = 0; tt < 16; ++tt) {
    f32x4 a[12];
#pragma unroll
    for (int g = 0; g < 12; ++g) a[g] = z4;
    const __bf16* kt  = kbase + (size_t)tt * 64 * HD;
    const __bf16* ktn = kbase + (size_t)(tt < 15 ? tt + 1 : tt) * 64 * HD;

#pragma unroll 1
    for (int h = 0; h < 12; h += 2) {
      // prefetch head h+1 (same tile) into n-buf
      const __bf16* kp1 = kt + (size_t)(h + 1) * HSTEP;
      const __bf16* qp1 = qbase + (size_t)(h + 1) * HSTEP;
      bf16x8 n0 = *(const bf16x8*)kp1;
      bf16x8 n1 = *(const bf16x8*)(kp1 + 32);
      bf16x8 n2 = *(const bf16x8*)qp1;
      bf16x8 n3 = *(const bf16x8*)(qp1 + 32);
      // compute head h from c-buf
      {
        f32x4 s = __builtin_amdgcn_mfma_f32_16x16x32_bf16(c0, c2, z4, 0, 0, 0);
        s = __builtin_amdgcn_mfma_f32_16x16x32_bf16(c1, c3, s, 0, 0, 0);
        PREMIX_ACC(h, s);
      }
      // prefetch head h+2 (or next tile's h=0) into c-buf
      const __bf16* kp2 = (h + 2 < 12) ? kt + (size_t)(h + 2) * HSTEP : ktn;
      const __bf16* qp2 = (h + 2 < 12) ? qbase + (size_t)(h + 2) * HSTEP : qbase;
      c0 = *(const bf16x8*)kp2;
      c1 = *(const bf16x8*)(kp2 + 32);
      c2 = *(const bf16x8*)qp2;
      c3 = *(const bf16x8*)(qp2 + 32);
      // compute head h+1 from n-buf
      {
        f32x4 s = __builtin_amdgcn_mfma_f32_16x16x32_bf16(n0, n2, z4, 0, 0, 0);
        s = __builtin_amdgcn_mfma_f32_16x16x32_bf16(n1, n3, s, 0, 0, 0);
        PREMIX_ACC(h + 1, s);
      }
    }
#pragma unroll
    for (int g = 0; g < 12; ++g)
      lsum[g] += __builtin_amdgcn_exp2f(a[g][0]) + __builtin_amdgcn_exp2f(a[g][1])
               + __builtin_amdgcn_exp2f(a[g][2]) + __builtin_amdgcn_exp2f(a[g][3]);
  }

  // reduce partials: over q-groups (same i), stash per wave, sum across waves
#pragma unroll
  for (int g = 0; g < 12; ++g) {
    float l = lsum[g];
    l += __shfl_xor(l, 16);
    l += __shfl_xor(l, 32);
    lsum[g] = l;
  }
  if (lane < 16) {
#pragma unroll
    for (int g = 0; g < 12; ++g) Lx[w][g][lane] = lsum[g];
  }
  __syncthreads();

  float linv[4][4];
#pragma unroll
  for (int c = 0; c < 4; ++c)
#pragma unroll
    for (int r = 0; r < 4; ++r) {
      const int g = q*4 + r;
      if (g < 12) {
        const int i = w*4 + c;
        float l = Lx[0][g][i] + Lx[1][g][i] + Lx[2][g][i] + Lx[3][g][i];
        linv[c][r] = 1.0f / (l * __builtin_amdgcn_exp2f(blS[g]));
      } else {
        linv[c][r] = 0.f;
      }
    }

  // ========== Phase B: unchanged from R8 (proven) =========================
  bf16x8 qf[3][2];
#pragma unroll
  for (int hh = 0; hh < 3; ++hh)
#pragma unroll
    for (int cc = 0; cc < 2; ++cc)
      qf[hh][cc] = *(const bf16x8*)(Qg + bbase + ((size_t)(h0+hh)*SEQ + i0 + n16)*HD + cc*32 + q*8);

  f32x4 oacc[3][4];
#pragma unroll
  for (int hh = 0; hh < 3; ++hh)
#pragma unroll
    for (int dc = 0; dc < 4; ++dc) oacc[hh][dc] = z4;

  bf16x8 kC[3][2], kN[3][2];
  f16x4 vC[3][4], vN[3][4];
#pragma unroll
  for (int hh = 0; hh < 3; ++hh) {
    const __bf16* kp = Kg + bbase + ((size_t)(h0+hh)*SEQ + n16)*HD + q*8;
    kC[hh][0] = *(const bf16x8*)kp;
    kC[hh][1] = *(const bf16x8*)(kp + 32);
  }

#pragma unroll 2
  for (int jt = 0; jt < SEQ/16; ++jt) {
    const int buf = jt & 1;
    const int jn = (jt < SEQ/16 - 1) ? jt + 1 : jt;
    // prefetch K(jt+1)
#pragma unroll
    for (int hh = 0; hh < 3; ++hh) {
      const __bf16* kp = Kg + bbase + ((size_t)(h0+hh)*SEQ + jn*16 + n16)*HD + q*8;
      kN[hh][0] = *(const bf16x8*)kp;
      kN[hh][1] = *(const bf16x8*)(kp + 32);
    }
    // prefetch V(jt) (consumed by PV next interval)
#pragma unroll
    for (int hh = 0; hh < 3; ++hh) {
      const _Float16* vb = Vt2 + (((size_t)(b*NH + h0 + hh)*64 + jt)*HD)*16;
#pragma unroll
      for (int dc = 0; dc < 4; ++dc)
        vN[hh][dc] = *(const f16x4*)(vb + (size_t)(dc*16 + n16)*16 + q*4);
    }
    // S(jt)
    __builtin_amdgcn_s_setprio(1);
#pragma unroll
    for (int hh = 0; hh < 3; ++hh) {
      f32x4 s = __builtin_amdgcn_mfma_f32_16x16x32_bf16(kC[hh][0], qf[hh][0], z4, 0, 0, 0);
      s = __builtin_amdgcn_mfma_f32_16x16x32_bf16(kC[hh][1], qf[hh][1], s, 0, 0, 0);
      f16x4 sh2 = { (_Float16)s[0], (_Float16)s[1], (_Float16)s[2], (_Float16)s[3] };
      *(f16x4*)&Sl[buf][h0+hh][n16*20 + q*4] = sh2;
    }
    __builtin_amdgcn_s_setprio(0);
    __syncthreads();
    // PV(jt-1) first: its LDS reads overlap the premix chain below
    if (jt > 0) {
      f16x4 pa[3];
#pragma unroll
      for (int hh = 0; hh < 3; ++hh)
        pa[hh] = *(const f16x4*)&Pl[1 - buf][n16*248 + (h0+hh)*20 + q*4];
      __builtin_amdgcn_s_setprio(1);
#pragma unroll
      for (int hh = 0; hh < 3; ++hh)
#pragma unroll
        for (int dc = 0; dc < 4; ++dc)
          oacc[hh][dc] = __builtin_amdgcn_mfma_f32_16x16x16f16(pa[hh], vC[hh][dc], oacc[hh][dc], 0, 0, 0);
      __builtin_amdgcn_s_setprio(0);
    }
    // premix -> exp2 -> normalize -> postmix -> Pl[buf]
#pragma unroll
    for (int c = 0; c < 4; ++c) {
      const int i = w*4 + c;
      f16x4 sf;
#pragma unroll
      for (int dd = 0; dd < 4; ++dd) {
        int h = q*4 + dd; if (h > 11) h = 11;
        sf[dd] = Sl[buf][h][i*20 + n16];
      }
      f32x4 sm = __builtin_amdgcn_mfma_f32_16x16x16f16(wlA, sf, blC, 0, 0, 0);
      f16x4 pnf;
#pragma unroll
      for (int r = 0; r < 4; ++r)
        pnf[r] = (_Float16)(__builtin_amdgcn_exp2f(sm[r]) * linv[c][r]);
      f32x4 p2 = __builtin_amdgcn_mfma_f32_16x16x16f16(wwA, pnf, bwC, 0, 0, 0);
      if (q < 3) {
#pragma unroll
        for (int r = 0; r < 4; ++r)
          Pl[buf][i*248 + (q*4 + r)*20 + n16] = (_Float16)p2[r];
      }
    }
    // rotate prefetch buffers
#pragma unroll
    for (int hh = 0; hh < 3; ++hh) {
      kC[hh][0] = kN[hh][0]; kC[hh][1] = kN[hh][1];
#pragma unroll
      for (int dc = 0; dc < 4; ++dc) vC[hh][dc] = vN[hh][dc];
    }
  }
  __syncthreads();
  // tail: PV(63) from Pl[1], vC = V(63)
#pragma unroll
  for (int hh = 0; hh < 3; ++hh) {
    const int g2 = h0 + hh;
    f16x4 pa = *(const f16x4*)&Pl[1][n16*248 + g2*20 + q*4];
#pragma unroll
    for (int dc = 0; dc < 4; ++dc)
      oacc[hh][dc] = __builtin_amdgcn_mfma_f32_16x16x16f16(pa, vC[hh][dc], oacc[hh][dc], 0, 0, 0);
  }

#pragma unroll
  for (int hh = 0; hh < 3; ++hh)
#pragma unroll
    for (int dc = 0; dc < 4; ++dc)
#pragma unroll
      for (int r = 0; r < 4; ++r)
        Aout[((size_t)(b*SEQ + i0 + q*4 + r))*DIM + (h0+hh)*HD + dc*16 + n16] =
            (__bf16)oacc[hh][dc][r];
}

// ---------------------------------------------------------------------------
// K3: output projection — global_load_lds staging (R8 proven).
// ---------------------------------------------------------------------------
__global__ __launch_bounds__(256) void gemm_proj(
    const __bf16* __restrict__ A, const __bf16* __restrict__ WpT,
    const float* __restrict__ bp, float* __restrict__ Out)
{
  __shared__ __bf16 As[128 * 32];
  __shared__ __bf16 Bs[128 * 32];

  const int t = threadIdx.x, lane = t & 63, w = t >> 6;
  const int n16 = lane & 15, q = lane >> 4;
  const int m0 = blockIdx.y * 128, n0 = blockIdx.x * 128;
  const int wm = (w >> 1) * 64, wn = (w & 1) * 64;

  const int srow = t >> 2, scol = (t & 3) * 8;
  const __bf16* Ag = A + (size_t)(m0 + srow) * DIM + scol;
  const __bf16* Bg = WpT + (size_t)(n0 + srow) * DIM + scol;
  __bf16* AsW0 = &As[w * 512];
  __bf16* AsW1 = &As[2048 + w * 512];
  __bf16* BsW0 = &Bs[w * 512];
  __bf16* BsW1 = &Bs[2048 + w * 512];

  f32x4 acc[4][4];
#pragma unroll
  for (int nt = 0; nt < 4; ++nt) {
    const float bpv = bp[n0 + wn + nt*16 + n16];
#pragma unroll
    for (int mt = 0; mt < 4; ++mt)
#pragma unroll
      for (int r = 0; r < 4; ++r) acc[mt][nt][r] = bpv;
  }

  for (int kb = 0; kb < DIM; kb += 32) {
    __syncthreads();
    gload_lds16(Ag + kb, AsW0);
    gload_lds16(Ag + (size_t)64 * DIM + kb, AsW1);
    gload_lds16(Bg + kb, BsW0);
    gload_lds16(Bg + (size_t)64 * DIM + kb, BsW1);
    __syncthreads();

    bf16x8 af[4], bg[4];
#pragma unroll
    for (int mt = 0; mt < 4; ++mt)
      af[mt] = *(const bf16x8*)&As[(wm + mt*16 + n16) * 32 + q*8];
#pragma unroll
    for (int nt = 0; nt < 4; ++nt)
      bg[nt] = *(const bf16x8*)&Bs[(wn + nt*16 + n16) * 32 + q*8];
#pragma unroll
    for (int mt = 0; mt < 4; ++mt)
#pragma unroll
      for (int nt = 0; nt < 4; ++nt)
        acc[mt][nt] = __builtin_amdgcn_mfma_f32_16x16x32_bf16(af[mt], bg[nt], acc[mt][nt], 0, 0, 0);
  }

#pragma unroll
  for (int nt = 0; nt < 4; ++nt) {
    const int n = n0 + wn + nt*16 + n16;
#pragma unroll
    for (int mt = 0; mt < 4; ++mt)
#pragma unroll
      for (int r = 0; r < 4; ++r) {
        const int row = m0 + wm + mt*16 + q*4 + r;
        Out[(size_t)row * DIM + n] = acc[mt][nt][r];
      }
  }
}

extern "C" void kernel_launch(void* const* d_in, const int* in_sizes, int n_in,
                              void* d_out, int out_size, void* d_ws, size_t ws_size,
                              hipStream_t stream) {
  const float* x  = (const float*)d_in[0];
  const float* Wq = (const float*)d_in[1];
  const float* Wk = (const float*)d_in[2];
  const float* Wv = (const float*)d_in[3];
  const float* Wl = (const float*)d_in[4];
  const float* bl = (const float*)d_in[5];
  const float* Ww = (const float*)d_in[6];
  const float* bw = (const float*)d_in[7];
  const float* Wp = (const float*)d_in[8];
  const float* bp = (const float*)d_in[9];

  char* p = (char*)d_ws;
  const size_t WSZ = (size_t)DIM * DIM * 2;                 // 1,179,648 B
  const size_t TSZ = (size_t)BATCH * NH * SEQ * HD * 2;     // 12,582,912 B
  __bf16*   WqT = (__bf16*)p;            p += WSZ;   // WqT|WkT|WvT contiguous:
  __bf16*   WkT = (__bf16*)p;            p += WSZ;   // = the 2304x768 B matrix
  __bf16*   WvT = (__bf16*)p;            p += WSZ;
  __bf16*   WpT = (__bf16*)p;            p += WSZ;
  __bf16*   Q   = (__bf16*)p;            p += TSZ;
  __bf16*   K   = (__bf16*)p;            p += TSZ;
  _Float16* V2  = (_Float16*)p;          p += TSZ;
  __bf16*   AO  = (__bf16*)p;            p += TSZ;
  __bf16*   Xb  = (__bf16*)p;            p += TSZ;

  xcvt<<<dim3((BATCH*SEQ*DIM)/(256*8)), 256, 0, stream>>>(x, Xb);
  wtrans<<<dim3(24, 24, 4), 256, 0, stream>>>(Wq, Wk, Wv, Wp, WqT, WkT, WvT, WpT);
  gemm_qkv<<<dim3(18, 64), 256, 0, stream>>>(Xb, WqT, Q, K, V2);
  attn_fused<<<dim3(BATCH, SEQ/16), 256, 0, stream>>>(Q, K, V2, Wl, bl, Ww, bw, AO);
  gemm_proj<<<dim3(6, 64), 256, 0, stream>>>(AO, WpT, bp, (float*)d_out);
}

// Round 14
// 420.258 us; speedup vs baseline: 1.1959x; 1.1959x over previous
//
#include <hip/hip_runtime.h>
#include <hip/hip_bf16.h>

#define DIM 768
#define NH 12
#define HD 64
#define SEQ 1024
#define BATCH 8
#define LOG2E 1.44269504f

typedef __bf16 bf16x8 __attribute__((ext_vector_type(8)));
typedef _Float16 f16x4 __attribute__((ext_vector_type(4)));
typedef float f32x4 __attribute__((ext_vector_type(4)));

// async global->LDS copy, 16 B per lane; LDS dest is wave-uniform base
// (+ lane*16 implicit). Source is per-lane.
__device__ __forceinline__ void gload_lds16(const __bf16* g, __bf16* l) {
  __builtin_amdgcn_global_load_lds(
      (const __attribute__((address_space(1))) void*)g,
      (__attribute__((address_space(3))) void*)l, 16, 0, 0);
}

// ---------------------------------------------------------------------------
// K0: fused prep — xcvt (blocks [0,3072)) + wtrans (blocks [3072,5376)).
// Internals of both halves byte-identical to the proven separate kernels;
// merging removes one launch boundary and runs them concurrently.
// ---------------------------------------------------------------------------
#define XCVT_BLOCKS ((BATCH*SEQ*DIM)/(256*8))   // 3072
__global__ __launch_bounds__(256) void prep(
    const float* __restrict__ X, __bf16* __restrict__ Xb,
    const float* __restrict__ Wq, const float* __restrict__ Wk,
    const float* __restrict__ Wv, const float* __restrict__ Wp,
    __bf16* __restrict__ Tq, __bf16* __restrict__ Tk,
    __bf16* __restrict__ Tv, __bf16* __restrict__ Tp)
{
  __shared__ float tile[32][33];
  const int t = threadIdx.x;
  if (blockIdx.x < XCVT_BLOCKS) {
    // ---- xcvt half: fp32 -> bf16, 8 elems/thread ----
    const size_t i = ((size_t)blockIdx.x * 256 + t) * 8;
    float4 a0 = *(const float4*)(X + i);
    float4 a1 = *(const float4*)(X + i + 4);
    bf16x8 v = { (__bf16)a0.x, (__bf16)a0.y, (__bf16)a0.z, (__bf16)a0.w,
                 (__bf16)a1.x, (__bf16)a1.y, (__bf16)a1.z, (__bf16)a1.w };
    *(bf16x8*)(Xb + i) = v;
  } else {
    // ---- wtrans half: transpose + cvt one 32x32 tile ----
    const int id = blockIdx.x - XCVT_BLOCKS;       // [0, 2304)
    const int z = id / 576, rem = id % 576;
    const int by = rem / 24, bx = rem % 24;
    const float* W = (z==0) ? Wq : (z==1) ? Wk : (z==2) ? Wv : Wp;
    __bf16* T = (z==0) ? Tq : (z==1) ? Tk : (z==2) ? Tv : Tp;
    const int tx = t & 31, ty = t >> 5;
    const int k0 = by * 32, n0 = bx * 32;
#pragma unroll
    for (int u = 0; u < 4; ++u)
      tile[ty + u*8][tx] = W[(size_t)(k0 + ty + u*8) * DIM + n0 + tx];
    __syncthreads();
#pragma unroll
    for (int u = 0; u < 4; ++u)
      T[(size_t)(n0 + ty + u*8) * DIM + k0 + tx] = (__bf16)tile[tx][ty + u*8];
  }
}

// ---------------------------------------------------------------------------
// K1: fused QKV projection, global_load_lds staging (R8 proven).
// ---------------------------------------------------------------------------
__global__ __launch_bounds__(256) void gemm_qkv(
    const __bf16* __restrict__ Xb, const __bf16* __restrict__ WT,
    __bf16* __restrict__ Qo, __bf16* __restrict__ Ko, _Float16* __restrict__ Vt2)
{
  __shared__ __bf16 As[128 * 32];
  __shared__ __bf16 Bs[128 * 32];

  const int t = threadIdx.x, lane = t & 63, w = t >> 6;
  const int n16 = lane & 15, q = lane >> 4;
  const int m0 = blockIdx.y * 128, n0 = blockIdx.x * 128;
  const int wm = (w >> 1) * 64, wn = (w & 1) * 64;

  const int srow = t >> 2, scol = (t & 3) * 8;
  const __bf16* Ag = Xb + (size_t)(m0 + srow) * DIM + scol;
  const __bf16* Bg = WT + (size_t)(n0 + srow) * DIM + scol;
  __bf16* AsW0 = &As[w * 512];
  __bf16* AsW1 = &As[2048 + w * 512];
  __bf16* BsW0 = &Bs[w * 512];
  __bf16* BsW1 = &Bs[2048 + w * 512];

  f32x4 acc[4][4];
#pragma unroll
  for (int mt = 0; mt < 4; ++mt)
#pragma unroll
    for (int nt = 0; nt < 4; ++nt) acc[mt][nt] = (f32x4){0.f,0.f,0.f,0.f};

  for (int kb = 0; kb < DIM; kb += 32) {
    __syncthreads();
    gload_lds16(Ag + kb, AsW0);
    gload_lds16(Ag + (size_t)64 * DIM + kb, AsW1);
    gload_lds16(Bg + kb, BsW0);
    gload_lds16(Bg + (size_t)64 * DIM + kb, BsW1);
    __syncthreads();

    bf16x8 af[4], bg[4];
#pragma unroll
    for (int mt = 0; mt < 4; ++mt)
      af[mt] = *(const bf16x8*)&As[(wm + mt*16 + n16) * 32 + q*8];
#pragma unroll
    for (int nt = 0; nt < 4; ++nt)
      bg[nt] = *(const bf16x8*)&Bs[(wn + nt*16 + n16) * 32 + q*8];
#pragma unroll
    for (int mt = 0; mt < 4; ++mt)
#pragma unroll
      for (int nt = 0; nt < 4; ++nt)
        acc[mt][nt] = __builtin_amdgcn_mfma_f32_16x16x32_bf16(af[mt], bg[nt], acc[mt][nt], 0, 0, 0);
  }

#pragma unroll
  for (int nt = 0; nt < 4; ++nt) {
    const int n = n0 + wn + nt*16 + n16;
    const int z = n / DIM, c = n % DIM;
    const int h = c >> 6, d = c & 63;
#pragma unroll
    for (int mt = 0; mt < 4; ++mt) {
#pragma unroll
      for (int r = 0; r < 4; ++r) {
        const int row = m0 + wm + mt*16 + q*4 + r;
        const int bb = row >> 10, ii = row & 1023;
        const float v = acc[mt][nt][r];
        if (z == 0)
          Qo[(((size_t)bb*NH + h)*SEQ + ii)*HD + d] = (__bf16)(v * 0.125f);
        else if (z == 1)
          Ko[(((size_t)bb*NH + h)*SEQ + ii)*HD + d] = (__bf16)v;
        else
          Vt2[((((size_t)bb*NH + h)*64 + (ii >> 4))*HD + d)*16 + (ii & 15)] = (_Float16)v;
      }
    }
  }
}

// ---------------------------------------------------------------------------
// K2: fused talking-heads attention — exact R8 configuration (measured 257 us
// within the 422.9 us total): f16 Sl, exp2-folded premix, lag-1 K/V register
// prefetch, one barrier per interval, setprio around MFMA clusters, PV
// issued before the premix chain, batch->XCD grid.
// ---------------------------------------------------------------------------
__global__ __launch_bounds__(256, 2) void attn_fused(
    const __bf16* __restrict__ Qg, const __bf16* __restrict__ Kg,
    const _Float16* __restrict__ Vt2,
    const float* __restrict__ Wl, const float* __restrict__ bl,
    const float* __restrict__ Ww, const float* __restrict__ bw,
    __bf16* __restrict__ Aout)
{
  __shared__ _Float16 Sl[2][12][324];    // f16 scores
  __shared__ _Float16 Pl[2][16 * 248];   // [buf][i*248 + g2*20 + j]

  const int t = threadIdx.x, lane = t & 63, w = t >> 6;
  const int n16 = lane & 15, q = lane >> 4;
  const int h0 = w * 3;
  const int b = blockIdx.x, i0 = blockIdx.y * 16;
  const size_t bbase = (size_t)b * NH * SEQ * HD;

  // premix weights with log2(e) folded in: exp(x) == exp2(x*log2e)
  f16x4 wlA, wwA;
  f32x4 blC, bwC;
#pragma unroll
  for (int j = 0; j < 4; ++j) {
    const int k = q*4 + j;
    wlA[j] = (n16 < 12 && k < 12) ? (_Float16)(Wl[n16*12 + k] * LOG2E) : (_Float16)0.f;
    wwA[j] = (n16 < 12 && k < 12) ? (_Float16)Ww[n16*12 + k] : (_Float16)0.f;
    blC[j] = (k < 12) ? bl[k] * LOG2E : 0.f;
    bwC[j] = (k < 12) ? bw[k] : 0.f;
  }

  bf16x8 qf[3][2];
#pragma unroll
  for (int hh = 0; hh < 3; ++hh)
#pragma unroll
    for (int cc = 0; cc < 2; ++cc)
      qf[hh][cc] = *(const bf16x8*)(Qg + bbase + ((size_t)(h0+hh)*SEQ + i0 + n16)*HD + cc*32 + q*8);

  const f32x4 z4 = {0.f, 0.f, 0.f, 0.f};

  // ---------------- Phase A: l[g][i], K prefetched one jt ahead ----------
  float lrun[4][4];
#pragma unroll
  for (int c = 0; c < 4; ++c)
#pragma unroll
    for (int r = 0; r < 4; ++r) lrun[c][r] = 0.f;

  bf16x8 kC[3][2], kN[3][2];
#pragma unroll
  for (int hh = 0; hh < 3; ++hh) {
    const __bf16* kp = Kg + bbase + ((size_t)(h0+hh)*SEQ + n16)*HD + q*8;
    kC[hh][0] = *(const bf16x8*)kp;
    kC[hh][1] = *(const bf16x8*)(kp + 32);
  }

#pragma unroll 2
  for (int jt = 0; jt < SEQ/16; ++jt) {
    const int buf = jt & 1;
    const int jn = (jt < SEQ/16 - 1) ? jt + 1 : jt;
#pragma unroll
    for (int hh = 0; hh < 3; ++hh) {
      const __bf16* kp = Kg + bbase + ((size_t)(h0+hh)*SEQ + jn*16 + n16)*HD + q*8;
      kN[hh][0] = *(const bf16x8*)kp;
      kN[hh][1] = *(const bf16x8*)(kp + 32);
    }
    __builtin_amdgcn_s_setprio(1);
#pragma unroll
    for (int hh = 0; hh < 3; ++hh) {
      f32x4 s = __builtin_amdgcn_mfma_f32_16x16x32_bf16(kC[hh][0], qf[hh][0], z4, 0, 0, 0);
      s = __builtin_amdgcn_mfma_f32_16x16x32_bf16(kC[hh][1], qf[hh][1], s, 0, 0, 0);
      f16x4 sh = { (_Float16)s[0], (_Float16)s[1], (_Float16)s[2], (_Float16)s[3] };
      *(f16x4*)&Sl[buf][h0+hh][n16*20 + q*4] = sh;
    }
    __builtin_amdgcn_s_setprio(0);
    __syncthreads();
#pragma unroll
    for (int c = 0; c < 4; ++c) {
      const int i = w*4 + c;
      f16x4 sf;
#pragma unroll
      for (int dd = 0; dd < 4; ++dd) {
        int h = q*4 + dd; if (h > 11) h = 11;
        sf[dd] = Sl[buf][h][i*20 + n16];
      }
      f32x4 sm = __builtin_amdgcn_mfma_f32_16x16x16f16(wlA, sf, blC, 0, 0, 0);
#pragma unroll
      for (int r = 0; r < 4; ++r) lrun[c][r] += __builtin_amdgcn_exp2f(sm[r]);
    }
#pragma unroll
    for (int hh = 0; hh < 3; ++hh) { kC[hh][0] = kN[hh][0]; kC[hh][1] = kN[hh][1]; }
  }

  float linv[4][4];
#pragma unroll
  for (int c = 0; c < 4; ++c)
#pragma unroll
    for (int r = 0; r < 4; ++r) {
      float l = lrun[c][r];
      l += __shfl_xor(l, 1);
      l += __shfl_xor(l, 2);
      l += __shfl_xor(l, 4);
      l += __shfl_xor(l, 8);
      linv[c][r] = 1.0f / l;
    }

  // ---------------- Phase B: 1 barrier/jt, PV lagged by one ----------------
  f32x4 oacc[3][4];
#pragma unroll
  for (int hh = 0; hh < 3; ++hh)
#pragma unroll
    for (int dc = 0; dc < 4; ++dc) oacc[hh][dc] = z4;

  f16x4 vC[3][4], vN[3][4];
#pragma unroll
  for (int hh = 0; hh < 3; ++hh) {
    const __bf16* kp = Kg + bbase + ((size_t)(h0+hh)*SEQ + n16)*HD + q*8;
    kC[hh][0] = *(const bf16x8*)kp;
    kC[hh][1] = *(const bf16x8*)(kp + 32);
  }

#pragma unroll 2
  for (int jt = 0; jt < SEQ/16; ++jt) {
    const int buf = jt & 1;
    const int jn = (jt < SEQ/16 - 1) ? jt + 1 : jt;
    // prefetch K(jt+1)
#pragma unroll
    for (int hh = 0; hh < 3; ++hh) {
      const __bf16* kp = Kg + bbase + ((size_t)(h0+hh)*SEQ + jn*16 + n16)*HD + q*8;
      kN[hh][0] = *(const bf16x8*)kp;
      kN[hh][1] = *(const bf16x8*)(kp + 32);
    }
    // prefetch V(jt) (consumed by PV next interval)
#pragma unroll
    for (int hh = 0; hh < 3; ++hh) {
      const _Float16* vb = Vt2 + (((size_t)(b*NH + h0 + hh)*64 + jt)*HD)*16;
#pragma unroll
      for (int dc = 0; dc < 4; ++dc)
        vN[hh][dc] = *(const f16x4*)(vb + (size_t)(dc*16 + n16)*16 + q*4);
    }
    // S(jt)
    __builtin_amdgcn_s_setprio(1);
#pragma unroll
    for (int hh = 0; hh < 3; ++hh) {
      f32x4 s = __builtin_amdgcn_mfma_f32_16x16x32_bf16(kC[hh][0], qf[hh][0], z4, 0, 0, 0);
      s = __builtin_amdgcn_mfma_f32_16x16x32_bf16(kC[hh][1], qf[hh][1], s, 0, 0, 0);
      f16x4 sh2 = { (_Float16)s[0], (_Float16)s[1], (_Float16)s[2], (_Float16)s[3] };
      *(f16x4*)&Sl[buf][h0+hh][n16*20 + q*4] = sh2;
    }
    __builtin_amdgcn_s_setprio(0);
    __syncthreads();
    // PV(jt-1) first: its LDS reads overlap the premix chain below
    if (jt > 0) {
      f16x4 pa[3];
#pragma unroll
      for (int hh = 0; hh < 3; ++hh)
        pa[hh] = *(const f16x4*)&Pl[1 - buf][n16*248 + (h0+hh)*20 + q*4];
      __builtin_amdgcn_s_setprio(1);
#pragma unroll
      for (int hh = 0; hh < 3; ++hh)
#pragma unroll
        for (int dc = 0; dc < 4; ++dc)
          oacc[hh][dc] = __builtin_amdgcn_mfma_f32_16x16x16f16(pa[hh], vC[hh][dc], oacc[hh][dc], 0, 0, 0);
      __builtin_amdgcn_s_setprio(0);
    }
    // premix -> exp2 -> normalize -> postmix -> Pl[buf]
#pragma unroll
    for (int c = 0; c < 4; ++c) {
      const int i = w*4 + c;
      f16x4 sf;
#pragma unroll
      for (int dd = 0; dd < 4; ++dd) {
        int h = q*4 + dd; if (h > 11) h = 11;
        sf[dd] = Sl[buf][h][i*20 + n16];
      }
      f32x4 sm = __builtin_amdgcn_mfma_f32_16x16x16f16(wlA, sf, blC, 0, 0, 0);
      f16x4 pnf;
#pragma unroll
      for (int r = 0; r < 4; ++r)
        pnf[r] = (_Float16)(__builtin_amdgcn_exp2f(sm[r]) * linv[c][r]);
      f32x4 p2 = __builtin_amdgcn_mfma_f32_16x16x16f16(wwA, pnf, bwC, 0, 0, 0);
      if (q < 3) {
#pragma unroll
        for (int r = 0; r < 4; ++r)
          Pl[buf][i*248 + (q*4 + r)*20 + n16] = (_Float16)p2[r];
      }
    }
    // rotate prefetch buffers
#pragma unroll
    for (int hh = 0; hh < 3; ++hh) {
      kC[hh][0] = kN[hh][0]; kC[hh][1] = kN[hh][1];
#pragma unroll
      for (int dc = 0; dc < 4; ++dc) vC[hh][dc] = vN[hh][dc];
    }
  }
  __syncthreads();
  // tail: PV(63) from Pl[1], vC = V(63)
#pragma unroll
  for (int hh = 0; hh < 3; ++hh) {
    const int g2 = h0 + hh;
    f16x4 pa = *(const f16x4*)&Pl[1][n16*248 + g2*20 + q*4];
#pragma unroll
    for (int dc = 0; dc < 4; ++dc)
      oacc[hh][dc] = __builtin_amdgcn_mfma_f32_16x16x16f16(pa, vC[hh][dc], oacc[hh][dc], 0, 0, 0);
  }

#pragma unroll
  for (int hh = 0; hh < 3; ++hh)
#pragma unroll
    for (int dc = 0; dc < 4; ++dc)
#pragma unroll
      for (int r = 0; r < 4; ++r)
        Aout[((size_t)(b*SEQ + i0 + q*4 + r))*DIM + (h0+hh)*HD + dc*16 + n16] =
            (__bf16)oacc[hh][dc][r];
}

// ---------------------------------------------------------------------------
// K3: output projection — global_load_lds staging (R8 proven).
// ---------------------------------------------------------------------------
__global__ __launch_bounds__(256) void gemm_proj(
    const __bf16* __restrict__ A, const __bf16* __restrict__ WpT,
    const float* __restrict__ bp, float* __restrict__ Out)
{
  __shared__ __bf16 As[128 * 32];
  __shared__ __bf16 Bs[128 * 32];

  const int t = threadIdx.x, lane = t & 63, w = t >> 6;
  const int n16 = lane & 15, q = lane >> 4;
  const int m0 = blockIdx.y * 128, n0 = blockIdx.x * 128;
  const int wm = (w >> 1) * 64, wn = (w & 1) * 64;

  const int srow = t >> 2, scol = (t & 3) * 8;
  const __bf16* Ag = A + (size_t)(m0 + srow) * DIM + scol;
  const __bf16* Bg = WpT + (size_t)(n0 + srow) * DIM + scol;
  __bf16* AsW0 = &As[w * 512];
  __bf16* AsW1 = &As[2048 + w * 512];
  __bf16* BsW0 = &Bs[w * 512];
  __bf16* BsW1 = &Bs[2048 + w * 512];

  f32x4 acc[4][4];
#pragma unroll
  for (int nt = 0; nt < 4; ++nt) {
    const float bpv = bp[n0 + wn + nt*16 + n16];
#pragma unroll
    for (int mt = 0; mt < 4; ++mt)
#pragma unroll
      for (int r = 0; r < 4; ++r) acc[mt][nt][r] = bpv;
  }

  for (int kb = 0; kb < DIM; kb += 32) {
    __syncthreads();
    gload_lds16(Ag + kb, AsW0);
    gload_lds16(Ag + (size_t)64 * DIM + kb, AsW1);
    gload_lds16(Bg + kb, BsW0);
    gload_lds16(Bg + (size_t)64 * DIM + kb, BsW1);
    __syncthreads();

    bf16x8 af[4], bg[4];
#pragma unroll
    for (int mt = 0; mt < 4; ++mt)
      af[mt] = *(const bf16x8*)&As[(wm + mt*16 + n16) * 32 + q*8];
#pragma unroll
    for (int nt = 0; nt < 4; ++nt)
      bg[nt] = *(const bf16x8*)&Bs[(wn + nt*16 + n16) * 32 + q*8];
#pragma unroll
    for (int mt = 0; mt < 4; ++mt)
#pragma unroll
      for (int nt = 0; nt < 4; ++nt)
        acc[mt][nt] = __builtin_amdgcn_mfma_f32_16x16x32_bf16(af[mt], bg[nt], acc[mt][nt], 0, 0, 0);
  }

#pragma unroll
  for (int nt = 0; nt < 4; ++nt) {
    const int n = n0 + wn + nt*16 + n16;
#pragma unroll
    for (int mt = 0; mt < 4; ++mt)
#pragma unroll
      for (int r = 0; r < 4; ++r) {
        const int row = m0 + wm + mt*16 + q*4 + r;
        Out[(size_t)row * DIM + n] = acc[mt][nt][r];
      }
  }
}

extern "C" void kernel_launch(void* const* d_in, const int* in_sizes, int n_in,
                              void* d_out, int out_size, void* d_ws, size_t ws_size,
                              hipStream_t stream) {
  const float* x  = (const float*)d_in[0];
  const float* Wq = (const float*)d_in[1];
  const float* Wk = (const float*)d_in[2];
  const float* Wv = (const float*)d_in[3];
  const float* Wl = (const float*)d_in[4];
  const float* bl = (const float*)d_in[5];
  const float* Ww = (const float*)d_in[6];
  const float* bw = (const float*)d_in[7];
  const float* Wp = (const float*)d_in[8];
  const float* bp = (const float*)d_in[9];

  char* p = (char*)d_ws;
  const size_t WSZ = (size_t)DIM * DIM * 2;                 // 1,179,648 B
  const size_t TSZ = (size_t)BATCH * NH * SEQ * HD * 2;     // 12,582,912 B
  __bf16*   WqT = (__bf16*)p;            p += WSZ;   // WqT|WkT|WvT contiguous:
  __bf16*   WkT = (__bf16*)p;            p += WSZ;   // = the 2304x768 B matrix
  __bf16*   WvT = (__bf16*)p;            p += WSZ;
  __bf16*   WpT = (__bf16*)p;            p += WSZ;
  __bf16*   Q   = (__bf16*)p;            p += TSZ;
  __bf16*   K   = (__bf16*)p;            p += TSZ;
  _Float16* V2  = (_Float16*)p;          p += TSZ;
  __bf16*   AO  = (__bf16*)p;            p += TSZ;
  __bf16*   Xb  = (__bf16*)p;            p += TSZ;

  prep<<<dim3(XCVT_BLOCKS + 2304), 256, 0, stream>>>(
      x, Xb, Wq, Wk, Wv, Wp, WqT, WkT, WvT, WpT);
  gemm_qkv<<<dim3(18, 64), 256, 0, stream>>>(Xb, WqT, Q, K, V2);
  attn_fused<<<dim3(BATCH, SEQ/16), 256, 0, stream>>>(Q, K, V2, Wl, bl, Ww, bw, AO);
  gemm_proj<<<dim3(6, 64), 256, 0, stream>>>(AO, WpT, bp, (float*)d_out);
}